// Round 4
// baseline (44.171 us; speedup 1.0000x reference)
//
#include <hip/hip_runtime.h>
#include <hip/hip_bf16.h>
#include <math.h>

#define D     128
#define NT    256            // B*T
#define HD    32
#define LD    32
#define NCH   4              // n's per score block
#define NC    (NT/NCH)       // 64 chunks
#define NROWS (NT*D)         // 32768

static __device__ inline unsigned short f2bf(float f) {
    __hip_bfloat16 b = __float2bfloat16(f);
    return *reinterpret_cast<unsigned short*>(&b);
}

// ---------------------------------------------------------------------------
// K1: pa[row][h] = b1[h] + z[row]·W1a[h,:],  pb[row][h] = z[row]·W1b[h,:]
//     ca2[row] = sum_h (w2[h]/2)*pa[row][h],  cb2[row] = sum_h (w2[h]/2)*pb[row][h]
// 32 rows per block, 1024 blocks. relu(x) = (x+|x|)/2 split: linear part is
// rank-1 and precomputed here; K2 only does the |.| part.
// ---------------------------------------------------------------------------
__global__ __launch_bounds__(256) void pab_kernel(
    const float* __restrict__ z, const float* __restrict__ W1,
    const float* __restrict__ b1, const float* __restrict__ W2,
    float* __restrict__ pa, float* __restrict__ pb,
    float* __restrict__ ca2, float* __restrict__ cb2)
{
    __shared__ float sW1a[HD][33];   // (h+l)%32 banks: conflict-free
    __shared__ float sW1b[HD][33];
    __shared__ float sz[32][33];

    const int t = threadIdx.x;
    for (int f = t; f < HD * 2 * LD; f += 256) {
        int hh = f >> 6, c = f & 63;
        float v = W1[f];
        if (c < LD) sW1a[hh][c] = v; else sW1b[hh][c - LD] = v;
    }
    const int row0 = blockIdx.x * 32;
    for (int f = t; f < 32 * LD; f += 256)
        sz[f >> 5][f & 31] = z[row0 * LD + f];

    const int h    = t & 31;
    const float bias = b1[h];
    const float w2h  = 0.5f * W2[h];
    __syncthreads();

    #pragma unroll
    for (int q = 0; q < 4; ++q) {
        int r = (t >> 5) + 8 * q;
        float aA = bias, aB = 0.f;
        #pragma unroll
        for (int l = 0; l < LD; ++l) {
            float zv = sz[r][l];
            aA = fmaf(zv, sW1a[h][l], aA);
            aB = fmaf(zv, sW1b[h][l], aB);
        }
        const int row = row0 + r;
        pa[row * HD + h] = aA;
        pb[row * HD + h] = aB;
        // 32-lane reductions for the rank-1 linear terms
        float vA = w2h * aA, vB = w2h * aB;
        #pragma unroll
        for (int m = 16; m >= 1; m >>= 1) {
            vA += __shfl_xor(vA, m);
            vB += __shfl_xor(vB, m);
        }
        if (h == 0) { ca2[row] = vA; cb2[row] = vB; }
    }
}

// ---------------------------------------------------------------------------
// K2 (hot): Spart[nc][i][j] = sum_{n in chunk} [ ca2[n,i] + cb2[n,j]
//                              + sum_h (w2[h]/2)*|pa[n,i,h]+pb[n,j,h]| ]
// 64x64 tile x NCH n's per block; lane=i, j wave-uniform (broadcast reads).
// Inner loop: v_add + v_fma(abs modifier) = 2 VALU/element.
// ---------------------------------------------------------------------------
__global__ __launch_bounds__(512) void scores_kernel(
    const float* __restrict__ pa, const float* __restrict__ pb,
    const float* __restrict__ ca2, const float* __restrict__ cb2,
    const float* __restrict__ W2,
    __hip_bfloat16* __restrict__ Spart, __hip_bfloat16* __restrict__ SpartT)
{
    __shared__ float spa[NCH][64][36];   // pad 36: b128 lane-distinct reads, clean
    __shared__ float spb[NCH][64][32];   // uniform (broadcast) reads: linear
    __shared__ float sS[64][65];         // transpose buffer

    const int t  = threadIdx.x;
    const int i0 = (blockIdx.x & 1) * 64;
    const int j0 = (blockIdx.x >> 1) * 64;
    const int nc = blockIdx.y;

    for (int f = t; f < NCH * 64 * 8; f += 512) {
        int h4 = f & 7, row = (f >> 3) & 63, nn = f >> 9;
        int n = nc * NCH + nn;
        *(float4*)&spa[nn][row][h4 * 4] =
            *(const float4*)&pa[((n * D) + i0 + row) * HD + h4 * 4];
        *(float4*)&spb[nn][row][h4 * 4] =
            *(const float4*)&pb[((n * D) + j0 + row) * HD + h4 * 4];
    }

    float w2r[HD];                        // uniform -> SGPRs
    #pragma unroll
    for (int hh = 0; hh < HD; ++hh) w2r[hh] = 0.5f * W2[hh];

    __syncthreads();

    const int lane = t & 63;
    const int jb   = __builtin_amdgcn_readfirstlane((t >> 6) * 8);

    float accA[8], accB[8];               // two h-chains per jj: hide fma latency
    #pragma unroll
    for (int jj = 0; jj < 8; ++jj) { accA[jj] = 0.f; accB[jj] = 0.f; }

    #pragma unroll 1
    for (int nn = 0; nn < NCH; ++nn) {
        float par[HD];                    // this lane's pa row
        #pragma unroll
        for (int k = 0; k < 8; ++k)
            *(float4*)&par[k * 4] = *(const float4*)&spa[nn][lane][k * 4];
        const int n = nc * NCH + nn;
        const float cai = ca2[n * D + i0 + lane];
        #pragma unroll
        for (int jj = 0; jj < 8; ++jj) {
            float pbv[HD];                // wave-uniform pb row (broadcast)
            #pragma unroll
            for (int k = 0; k < 8; ++k)
                *(float4*)&pbv[k * 4] = *(const float4*)&spb[nn][jb + jj][k * 4];
            float a = accA[jj] + cai;
            float b = accB[jj] + cb2[n * D + j0 + jb + jj];
            #pragma unroll
            for (int hh = 0; hh < 16; ++hh)
                a = fmaf(w2r[hh], fabsf(par[hh] + pbv[hh]), a);
            #pragma unroll
            for (int hh = 16; hh < 32; ++hh)
                b = fmaf(w2r[hh], fabsf(par[hh] + pbv[hh]), b);
            accA[jj] = a; accB[jj] = b;
        }
    }

    // ---- epilogue: bf16 partials, both orientations, coalesced ----
    {   // SpartT[nc][j][i]; lanes = consecutive i
        __hip_bfloat16* SpT = SpartT + ((size_t)nc * D + j0 + jb) * D + i0;
        #pragma unroll
        for (int jj = 0; jj < 8; ++jj)
            SpT[jj * D + lane] = __float2bfloat16(accA[jj] + accB[jj]);
    }
    #pragma unroll
    for (int jj = 0; jj < 8; ++jj)
        sS[lane][jb + jj] = accA[jj] + accB[jj];
    __syncthreads();
    {   // Spart[nc][i][j] via LDS transpose, 16B stores
        int ir = t >> 3;
        int jc = (t & 7) * 8;
        unsigned int pk[4];
        #pragma unroll
        for (int k = 0; k < 4; ++k) {
            unsigned int lo = f2bf(sS[ir][jc + 2 * k]);
            unsigned int hi = f2bf(sS[ir][jc + 2 * k + 1]);
            pk[k] = (hi << 16) | lo;
        }
        __hip_bfloat16* Sp = Spart + ((size_t)nc * D + i0 + ir) * D + j0 + jc;
        *(uint4*)Sp = *(uint4*)pk;
    }
}

// ---------------------------------------------------------------------------
// K3: reduce bf16 partials (both orientations coalesced), antisym, sigmoids,
// Wm. b2 cancels exactly in S - S^T; b1 is inside pa via K1.
// ---------------------------------------------------------------------------
__global__ __launch_bounds__(256) void finalize_kernel(
    const __hip_bfloat16* __restrict__ Spart,
    const __hip_bfloat16* __restrict__ SpartT,
    const float* __restrict__ Wmag, float* __restrict__ out)
{
    const int t = blockIdx.x * 256 + threadIdx.x;   // 0..16383
    const int i = t >> 7, j = t & 127;

    float s = 0.f;
    #pragma unroll 4
    for (int nc = 0; nc < NC; ++nc) {
        float a = __bfloat162float(Spart [(size_t)nc * D * D + t]);  // S[i][j]
        float b = __bfloat162float(SpartT[(size_t)nc * D * D + t]);  // S[j][i]
        s += a - b;
    }
    float av  = s * (1.0f / 256.0f);                // mean over n; TAU = 1
    float dir = 1.0f / (1.0f + __expf(-av));
    float wm  = 0.5f * (Wmag[i * D + j] + Wmag[j * D + i]);
    float A;
    if (i == j) { wm = 0.f; A = 0.f; }
    else        { A = dir / (1.0f + __expf(-wm)); }
    out[t]         = A;
    out[D * D + t] = wm;
}

extern "C" void kernel_launch(void* const* d_in, const int* in_sizes, int n_in,
                              void* d_out, int out_size, void* d_ws, size_t ws_size,
                              hipStream_t stream)
{
    const float* z    = (const float*)d_in[0];   // (4,64,128,32)
    const float* Wmag = (const float*)d_in[1];   // (128,128)
    const float* W1   = (const float*)d_in[2];   // (32,64)
    const float* b1   = (const float*)d_in[3];   // (32,)
    const float* W2   = (const float*)d_in[4];   // (1,32)
    // d_in[5] = b2: cancels in scores - scores^T.

    float* pa   = (float*)d_ws;                          // 4 MB
    float* pb   = pa + (size_t)NROWS * HD;               // 4 MB
    float* ca2  = pb + (size_t)NROWS * HD;               // 128 KB
    float* cb2  = ca2 + NROWS;                           // 128 KB
    __hip_bfloat16* Spart  = (__hip_bfloat16*)(cb2 + NROWS);     // 2 MB
    __hip_bfloat16* SpartT = Spart + (size_t)NC * D * D;         // 2 MB
    float* out = (float*)d_out;

    pab_kernel<<<NROWS / 32, 256, 0, stream>>>(z, W1, b1, W2, pa, pb, ca2, cb2);
    scores_kernel<<<dim3(4, NC), 512, 0, stream>>>(pa, pb, ca2, cb2, W2, Spart, SpartT);
    finalize_kernel<<<(D * D) / 256, 256, 0, stream>>>(Spart, SpartT, Wmag, out);
}